// Round 4
// baseline (689.980 us; speedup 1.0000x reference)
//
#include <hip/hip_runtime.h>
#include <float.h>

// Problem constants
#define B 256
#define S 512
#define D 768
#define P 100
#define K 5
#define SPLIT 4
#define SCHUNK (S / SPLIT)   // 128
#define D4 (D / 4)           // 192

// Workspace layout: first (B+1) ints are counters (zeroed via hipMemsetAsync),
// then float data at 16-byte-aligned offsets (in floats):
#define PART_OFF 512                       // [SPLIT][B][D] partial maxes
#define PN_OFF   (PART_OFF + SPLIT * B * D)// [P][D] prompt_norm

// Output layout (float offsets): similarity, selected_key, reduce_sim, idx
#define SIM_OFF 0
#define SEL_OFF (B * P)                    // 25600
#define RS_OFF  (SEL_OFF + B * K * D)      // 1008640
#define IDX_OFF (RS_OFF + 1)               // 1008641

__device__ inline float4 fmax4(float4 a, float4 b) {
    return make_float4(fmaxf(a.x, b.x), fmaxf(a.y, b.y),
                       fmaxf(a.z, b.z), fmaxf(a.w, b.w));
}

__device__ inline float precise_rsqrt(float tot) {
    float x = fmaxf(tot, 1e-12f);
    float r = rsqrtf(x);
    r = r * (1.5f - 0.5f * x * r * r);   // one Newton step
    return r;
}

// Single fused kernel, grid = P + B*SPLIT blocks x 192 threads.
//  blocks [0,P):        prompt_norm rows (dispatched first), signal pn_done
//  blocks [P, P+B*SPLIT): partmax chunk; the LAST arriver of row b's 4 chunks
//                       waits for pn_done==P then does combine+norm+sim+top5
__global__ __launch_bounds__(192) void k_all(const float* __restrict__ x,
                                             const float* __restrict__ pk,
                                             float* __restrict__ ws,
                                             float* __restrict__ out) {
    int* cnt     = (int*)ws;      // [B] per-row chunk counters
    int* pn_done = cnt + B;       // prompt-norm completion counter
    const int blk = blockIdx.x;
    const int t = threadIdx.x;    // 0..191
    const int lane = t & 63, w = t >> 6;

    __shared__ float lds[3];
    __shared__ float xs[D];
    __shared__ float simbuf[P];
    __shared__ float topv[K];
    __shared__ int   topi[K];
    __shared__ int   is_last;

    if (blk < P) {
        // ---- prompt_norm = l2_normalize(prompt_key[p])
        const int p = blk;
        float4 v = ((const float4*)pk)[(size_t)p * D4 + t];
        float sq = v.x * v.x + v.y * v.y + v.z * v.z + v.w * v.w;
        for (int off = 32; off; off >>= 1) sq += __shfl_down(sq, off);
        if (lane == 0) lds[w] = sq;
        __syncthreads();
        float tot = lds[0] + lds[1] + lds[2];
        float r = precise_rsqrt(tot);
        ((float4*)(ws + PN_OFF))[(size_t)p * D4 + t] =
            make_float4(v.x * r, v.y * r, v.z * r, v.w * r);
        if (p == 0 && t == 0) out[RS_OFF] = 0.0f;  // zero reduce_sim accum
        __syncthreads();
        if (t == 0) { __threadfence(); atomicAdd(pn_done, 1); }
        return;
    }

    // ---- partial max over seq chunk: each thread owns one float4 column
    const int bs = blk - P;
    const int b  = bs >> 2;       // / SPLIT
    const int sp = bs & 3;        // % SPLIT
    {
        const float4* src = (const float4*)(x + (size_t)b * S * D)
                            + (size_t)(sp * SCHUNK) * D4 + t;
        float4 m0 = make_float4(-FLT_MAX, -FLT_MAX, -FLT_MAX, -FLT_MAX);
        float4 m1 = m0, m2 = m0, m3 = m0;
        for (int s = 0; s < SCHUNK; s += 4) {
            float4 a0 = src[(size_t)(s + 0) * D4];
            float4 a1 = src[(size_t)(s + 1) * D4];
            float4 a2 = src[(size_t)(s + 2) * D4];
            float4 a3 = src[(size_t)(s + 3) * D4];
            m0 = fmax4(m0, a0);
            m1 = fmax4(m1, a1);
            m2 = fmax4(m2, a2);
            m3 = fmax4(m3, a3);
        }
        float4 m = fmax4(fmax4(m0, m1), fmax4(m2, m3));
        ((float4*)(ws + PART_OFF))[(size_t)(sp * B + b) * D4 + t] = m;
    }
    __syncthreads();
    if (t == 0) {
        __threadfence();                       // publish our partial
        int old = atomicAdd(&cnt[b], 1);       // device-scope RMW
        is_last = (old == SPLIT - 1);
    }
    __syncthreads();
    if (!is_last) return;

    // ---- last arriver for row b: wait for prompt_norm, then fused tail
    if (t == 0) {
        while (__hip_atomic_load(pn_done, __ATOMIC_ACQUIRE,
                                 __HIP_MEMORY_SCOPE_AGENT) < P)
            __builtin_amdgcn_s_sleep(1);
    }
    __syncthreads();
    __threadfence();   // acquire: make all partials + pn rows visible

    // combine SPLIT partial maxes for row b, l2-normalize into LDS (t==D4 lanes)
    const float4* part = (const float4*)(ws + PART_OFF);
    float4 m = part[(size_t)b * D4 + t];
    #pragma unroll
    for (int spp = 1; spp < SPLIT; ++spp)
        m = fmax4(m, part[(size_t)(spp * B + b) * D4 + t]);
    float sq = m.x * m.x + m.y * m.y + m.z * m.z + m.w * m.w;
    for (int off = 32; off; off >>= 1) sq += __shfl_down(sq, off);
    if (lane == 0) lds[w] = sq;
    __syncthreads();
    float tot = lds[0] + lds[1] + lds[2];
    float r = precise_rsqrt(tot);
    ((float4*)xs)[t] = make_float4(m.x * r, m.y * r, m.z * r, m.w * r);
    __syncthreads();

    // similarity: wave w handles p = w, w+3, w+6, ... (3 waves)
    const float* pn = ws + PN_OFF;
    for (int j = 0; j < 34; ++j) {
        const int p = w + 3 * j;
        if (p >= P) break;
        float acc = 0.f;
        #pragma unroll
        for (int jj = 0; jj < 12; ++jj) {
            const int d = lane + 64 * jj;
            acc += pn[(size_t)p * D + d] * xs[d];
        }
        for (int off = 32; off; off >>= 1) acc += __shfl_down(acc, off);
        if (lane == 0) {
            simbuf[p] = acc;
            out[SIM_OFF + (size_t)b * P + p] = acc;
        }
    }
    __syncthreads();

    // top-5 with jax tie-breaking (ties -> lower index), wave 0 only
    if (w == 0) {
        float v0 = (lane < P) ? simbuf[lane] : -FLT_MAX;
        int   i0 = lane;
        int   i1 = lane + 64;
        float v1 = (i1 < P) ? simbuf[i1] : -FLT_MAX;
        for (int k = 0; k < K; ++k) {
            float bv; int bi;
            if (v0 > v1 || (v0 == v1 && i0 < i1)) { bv = v0; bi = i0; }
            else                                  { bv = v1; bi = i1; }
            for (int off = 32; off; off >>= 1) {
                float ov = __shfl_xor(bv, off);
                int   oi = __shfl_xor(bi, off);
                if (ov > bv || (ov == bv && oi < bi)) { bv = ov; bi = oi; }
            }
            if (lane == 0) { topv[k] = bv; topi[k] = bi; }
            if (bi == i0) v0 = -FLT_MAX;
            else if (bi == i1) v1 = -FLT_MAX;
        }
    }
    __syncthreads();

    // idx written as float values (whole out buffer is read back as fp32)
    if (t < K) out[IDX_OFF + (size_t)b * K + t] = (float)topi[t];

    // reduce_sim: sum_d selected*x_norm == similarity at the selected index
    if (t == 0) {
        float s = topv[0] + topv[1] + topv[2] + topv[3] + topv[4];
        atomicAdd(out + RS_OFF, s * (1.0f / (float)B));
    }

    // selected_key = prompt_norm[idx]  (5 rows x 192 float4)
    const float4* pn4 = (const float4*)pn;
    float4* sel4 = (float4*)(out + SEL_OFF) + (size_t)b * (K * D4);
    for (int i = t; i < K * D4; i += 192) {
        const int k = i / D4;
        const int e = i - k * D4;
        sel4[i] = pn4[(size_t)topi[k] * D4 + e];
    }
}

extern "C" void kernel_launch(void* const* d_in, const int* in_sizes, int n_in,
                              void* d_out, int out_size, void* d_ws, size_t ws_size,
                              hipStream_t stream) {
    const float* x_embed    = (const float*)d_in[0];
    const float* prompt_key = (const float*)d_in[1];
    float* out = (float*)d_out;
    float* ws  = (float*)d_ws;

    // zero the (B+1) int counters (ws is poisoned 0xAA before every launch)
    hipMemsetAsync(ws, 0, (B + 1) * sizeof(int), stream);
    k_all<<<P + B * SPLIT, 192, 0, stream>>>(x_embed, prompt_key, ws, out);
}

// Round 5
// 541.485 us; speedup vs baseline: 1.2742x; 1.2742x over previous
//
#include <hip/hip_runtime.h>
#include <float.h>

// Problem constants
#define B 256
#define S 512
#define D 768
#define P 100
#define K 5
#define SPLIT 4
#define SCHUNK (S / SPLIT)   // 128
#define D4 (D / 4)           // 192

// Workspace layout (float offsets)
#define PART_OFF 0                         // [SPLIT][B][D] partial maxes
#define PN_OFF   (SPLIT * B * D)           // [P][D] prompt_norm

// Output layout (float offsets): similarity, selected_key, reduce_sim, idx
#define SIM_OFF 0
#define SEL_OFF (B * P)                    // 25600
#define RS_OFF  (SEL_OFF + B * K * D)      // 1008640
#define IDX_OFF (RS_OFF + 1)               // 1008641

__device__ inline float4 fmax4(float4 a, float4 b) {
    return make_float4(fmaxf(a.x, b.x), fmaxf(a.y, b.y),
                       fmaxf(a.z, b.z), fmaxf(a.w, b.w));
}

__device__ inline float precise_rsqrt(float tot) {
    float x = fmaxf(tot, 1e-12f);
    float r = rsqrtf(x);
    r = r * (1.5f - 0.5f * x * r * r);   // one Newton step
    return r;
}

// ---------------- Kernel 1: partmax (bandwidth) + prompt_norm (tail blocks)
// grid = B*SPLIT + P blocks x 192 threads. NO cross-block sync (R4 showed
// device-scope fences cost ~200us in L2 coherence traffic on gfx950).
__global__ __launch_bounds__(192) void k_stage1(const float* __restrict__ x,
                                                const float* __restrict__ pk,
                                                float* __restrict__ ws,
                                                float* __restrict__ out) {
    __shared__ float lds[3];
    const int blk = blockIdx.x;
    const int t = threadIdx.x;   // 0..191

    if (blk < B * SPLIT) {
        // ---- partial max over seq chunk: each thread owns one float4 column
        const int b  = blk >> 2;      // / SPLIT
        const int sp = blk & 3;       // % SPLIT
        const float4* src = (const float4*)(x + (size_t)b * S * D)
                            + (size_t)(sp * SCHUNK) * D4 + t;
        float4 m0 = make_float4(-FLT_MAX, -FLT_MAX, -FLT_MAX, -FLT_MAX);
        float4 m1 = m0, m2 = m0, m3 = m0;
        float4 m4 = m0, m5 = m0, m6 = m0, m7 = m0;
        for (int s = 0; s < SCHUNK; s += 8) {
            // 8 independent 16B loads in flight per thread (MLP)
            float4 a0 = src[(size_t)(s + 0) * D4];
            float4 a1 = src[(size_t)(s + 1) * D4];
            float4 a2 = src[(size_t)(s + 2) * D4];
            float4 a3 = src[(size_t)(s + 3) * D4];
            float4 a4 = src[(size_t)(s + 4) * D4];
            float4 a5 = src[(size_t)(s + 5) * D4];
            float4 a6 = src[(size_t)(s + 6) * D4];
            float4 a7 = src[(size_t)(s + 7) * D4];
            m0 = fmax4(m0, a0);
            m1 = fmax4(m1, a1);
            m2 = fmax4(m2, a2);
            m3 = fmax4(m3, a3);
            m4 = fmax4(m4, a4);
            m5 = fmax4(m5, a5);
            m6 = fmax4(m6, a6);
            m7 = fmax4(m7, a7);
        }
        float4 m = fmax4(fmax4(fmax4(m0, m1), fmax4(m2, m3)),
                         fmax4(fmax4(m4, m5), fmax4(m6, m7)));
        ((float4*)(ws + PART_OFF))[(size_t)(sp * B + b) * D4 + t] = m;
    } else {
        // ---- prompt_norm = l2_normalize(prompt_key[p])
        const int p = blk - B * SPLIT;
        float4 v = ((const float4*)pk)[(size_t)p * D4 + t];
        float sq = v.x * v.x + v.y * v.y + v.z * v.z + v.w * v.w;
        for (int off = 32; off; off >>= 1) sq += __shfl_down(sq, off);
        const int lane = t & 63, w = t >> 6;
        if (lane == 0) lds[w] = sq;
        __syncthreads();
        float tot = lds[0] + lds[1] + lds[2];
        float r = precise_rsqrt(tot);
        ((float4*)(ws + PN_OFF))[(size_t)p * D4 + t] =
            make_float4(v.x * r, v.y * r, v.z * r, v.w * r);
        // zero the reduce_sim accumulator (d_out is re-poisoned every launch)
        if (p == 0 && t == 0) out[RS_OFF] = 0.0f;
    }
}

// ---------------- Kernel 2 (fused): combine+normalize+sim+top5+outputs -----
// grid = B blocks x 512 threads (8 waves) — extra waves hide L2-hit latency
// in the dot-product phase.
__global__ __launch_bounds__(512) void k_fused(const float* __restrict__ ws,
                                               float* __restrict__ out) {
    __shared__ float xs[D];
    __shared__ float simbuf[P];
    __shared__ float lds[8];
    __shared__ float topv[K];
    __shared__ int   topi[K];
    const int b = blockIdx.x, t = threadIdx.x;
    const int w = t >> 6, lane = t & 63;

    // combine SPLIT partial maxes for row b, then l2-normalize into LDS
    float4 m = make_float4(0.f, 0.f, 0.f, 0.f);
    float sq = 0.f;
    if (t < D4) {
        const float4* part = (const float4*)(ws + PART_OFF);
        m = part[(size_t)b * D4 + t];
        #pragma unroll
        for (int sp = 1; sp < SPLIT; ++sp)
            m = fmax4(m, part[(size_t)(sp * B + b) * D4 + t]);
        sq = m.x * m.x + m.y * m.y + m.z * m.z + m.w * m.w;
    }
    for (int off = 32; off; off >>= 1) sq += __shfl_down(sq, off);
    if (lane == 0) lds[w] = sq;
    __syncthreads();
    float tot = lds[0] + lds[1] + lds[2] + lds[3];  // only waves 0-3 hold D4
    float r = precise_rsqrt(tot);
    if (t < D4)
        ((float4*)xs)[t] = make_float4(m.x * r, m.y * r, m.z * r, m.w * r);
    __syncthreads();

    // similarity: wave w handles p = w, w+8, ..., (13 dots for w<4, 12 for w>=4)
    const float* pn = ws + PN_OFF;
    for (int j = 0; j < 13; ++j) {
        const int p = w + 8 * j;
        if (p >= P) break;
        float acc = 0.f;
        #pragma unroll
        for (int jj = 0; jj < 12; ++jj) {
            const int d = lane + 64 * jj;
            acc += pn[(size_t)p * D + d] * xs[d];
        }
        for (int off = 32; off; off >>= 1) acc += __shfl_down(acc, off);
        if (lane == 0) {
            simbuf[p] = acc;
            out[SIM_OFF + (size_t)b * P + p] = acc;
        }
    }
    __syncthreads();

    // top-5 with jax tie-breaking (ties -> lower index), wave 0 only
    if (w == 0) {
        float v0 = (lane < P) ? simbuf[lane] : -FLT_MAX;
        int   i0 = lane;
        int   i1 = lane + 64;
        float v1 = (i1 < P) ? simbuf[i1] : -FLT_MAX;
        for (int k = 0; k < K; ++k) {
            float bv; int bi;
            if (v0 > v1 || (v0 == v1 && i0 < i1)) { bv = v0; bi = i0; }
            else                                  { bv = v1; bi = i1; }
            for (int off = 32; off; off >>= 1) {
                float ov = __shfl_xor(bv, off);
                int   oi = __shfl_xor(bi, off);
                if (ov > bv || (ov == bv && oi < bi)) { bv = ov; bi = oi; }
            }
            if (lane == 0) { topv[k] = bv; topi[k] = bi; }
            if (bi == i0) v0 = -FLT_MAX;
            else if (bi == i1) v1 = -FLT_MAX;
        }
    }
    __syncthreads();

    // idx written as float values (whole out buffer is read back as fp32)
    if (t < K) out[IDX_OFF + (size_t)b * K + t] = (float)topi[t];

    // reduce_sim: sum_d selected*x_norm == similarity at the selected index
    if (t == 0) {
        float s = topv[0] + topv[1] + topv[2] + topv[3] + topv[4];
        atomicAdd(out + RS_OFF, s * (1.0f / (float)B));
    }

    // selected_key = prompt_norm[idx]  (5 rows x 192 float4)
    const float4* pn4 = (const float4*)pn;
    float4* sel4 = (float4*)(out + SEL_OFF) + (size_t)b * (K * D4);
    for (int i = t; i < K * D4; i += 512) {
        const int k = i / D4;
        const int e = i - k * D4;
        sel4[i] = pn4[(size_t)topi[k] * D4 + e];
    }
}

extern "C" void kernel_launch(void* const* d_in, const int* in_sizes, int n_in,
                              void* d_out, int out_size, void* d_ws, size_t ws_size,
                              hipStream_t stream) {
    const float* x_embed    = (const float*)d_in[0];
    const float* prompt_key = (const float*)d_in[1];
    float* out = (float*)d_out;
    float* ws  = (float*)d_ws;

    k_stage1<<<B * SPLIT + P, 192, 0, stream>>>(x_embed, prompt_key, ws, out);
    k_fused<<<B, 512, 0, stream>>>(ws, out);
}